// Round 1
// baseline (316.244 us; speedup 1.0000x reference)
//
#include <hip/hip_runtime.h>
#include <cmath>
#include <cfloat>
#include <climits>

// Match numpy's un-fused f32 arithmetic as closely as possible: the matching
// output is binary, so order decisions near the k-th-smallest boundary must
// agree with the reference. No FMA contraction anywhere in this TU.
#pragma clang fp contract(off)

static constexpr int BS = 16;
static constexpr int Qn = 4000;
static constexpr int Cn = 80;
static constexpr int Gn = 128;
static constexpr float kEPS = 1e-8f;

__device__ __forceinline__ bool pless(float av, int ai, float bv, int bi) {
    return (av < bv) || (av == bv && ai < bi);
}

// ---------------------------------------------------------------------------
// Phase A: cost[b][g][q]  ->  out[b][0][g][q]
// block: 256 threads over a q-tile; blockIdx.y selects a 16-gt chunk.
// ---------------------------------------------------------------------------
__global__ __launch_bounds__(256) void kA_cost(
    const float* __restrict__ logits,   // [BS][Qn][Cn]
    const float* __restrict__ boxes,    // [BS][Qn][4] cxcywh
    const int*   __restrict__ labels,   // [BS][Gn]
    const float* __restrict__ tboxes,   // [BS][Gn][4] cxcywh
    float* __restrict__ out)            // [BS][2][Gn][Qn]
{
    const int b  = blockIdx.z;
    const int g0 = blockIdx.y * 16;
    const int q  = blockIdx.x * 256 + threadIdx.x;

    __shared__ float s_cx[16], s_cy[16], s_w[16], s_h[16];
    __shared__ float s_x0[16], s_y0[16], s_x1[16], s_y1[16], s_ar[16];
    __shared__ int   s_lab[16];
    if (threadIdx.x < 16) {
        const int g = g0 + threadIdx.x;
        const float* tb = tboxes + (size_t)(b * Gn + g) * 4;
        float cx = tb[0], cy = tb[1], w = tb[2], h = tb[3];
        float x0 = cx - 0.5f * w, y0 = cy - 0.5f * h;
        float x1 = cx + 0.5f * w, y1 = cy + 0.5f * h;
        s_cx[threadIdx.x] = cx; s_cy[threadIdx.x] = cy;
        s_w[threadIdx.x]  = w;  s_h[threadIdx.x]  = h;
        s_x0[threadIdx.x] = x0; s_y0[threadIdx.x] = y0;
        s_x1[threadIdx.x] = x1; s_y1[threadIdx.x] = y1;
        s_ar[threadIdx.x] = (x1 - x0) * (y1 - y0);
        s_lab[threadIdx.x] = labels[b * Gn + g];
    }
    __syncthreads();
    if (q >= Qn) return;

    const float4 bb = *reinterpret_cast<const float4*>(boxes + (size_t)(b * Qn + q) * 4);
    const float cx = bb.x, cy = bb.y, w = bb.z, h = bb.w;
    const float x0 = cx - 0.5f * w, y0 = cy - 0.5f * h;
    const float x1 = cx + 0.5f * w, y1 = cy + 0.5f * h;
    const float area1 = (x1 - x0) * (y1 - y0);

    const float* lrow = logits + (size_t)(b * Qn + q) * Cn;
    float* orow = out + (size_t)(b * 2) * Gn * Qn + q;   // [b][0][.][q]

    for (int gi = 0; gi < 16; ++gi) {
        const int g = g0 + gi;
        // focal class cost
        const float l = lrow[s_lab[gi]];
        const float p = 1.0f / (1.0f + expf(-l));
        const float neg = (0.75f * (p * p)) * (-log1pf(-p + kEPS));
        const float pos = (0.25f * ((1.0f - p) * (1.0f - p))) * (-logf(p + kEPS));
        const float cls = pos - neg;
        // L1 in cxcywh
        const float l1 = ((fabsf(cx - s_cx[gi]) + fabsf(cy - s_cy[gi]))
                          + fabsf(w - s_w[gi])) + fabsf(h - s_h[gi]);
        // IoU / GIoU in xyxy
        const float ltx = fmaxf(x0, s_x0[gi]), lty = fmaxf(y0, s_y0[gi]);
        const float rbx = fminf(x1, s_x1[gi]), rby = fminf(y1, s_y1[gi]);
        const float iw = fmaxf(rbx - ltx, 0.0f), ih = fmaxf(rby - lty, 0.0f);
        const float inter = iw * ih;
        const float uni = (area1 + s_ar[gi]) - inter;
        const float iou = inter / (uni + kEPS);
        const float cltx = fminf(x0, s_x0[gi]), clty = fminf(y0, s_y0[gi]);
        const float crbx = fmaxf(x1, s_x1[gi]), crby = fmaxf(y1, s_y1[gi]);
        const float cw = fmaxf(crbx - cltx, 0.0f), ch = fmaxf(crby - clty, 0.0f);
        const float areac = cw * ch;
        const float giou = iou - (areac - uni) / (areac + kEPS);

        const float cost = (5.0f * l1 + 2.0f * cls) + 2.0f * (-giou);
        orow[(size_t)g * Qn] = cost;
    }
}

// ---------------------------------------------------------------------------
// Phase B: per (b,g) row: top-10 IoU sum -> k; k-th smallest (cost, idx) pair.
// 16-slot sorted lists kept fully register-resident (static indexing only).
// ---------------------------------------------------------------------------
__device__ __forceinline__ void ins16_pair(float (&cv)[16], int (&ci)[16], float v, int i) {
    bool le[16];
#pragma unroll
    for (int j = 0; j < 16; ++j) le[j] = pless(cv[j], ci[j], v, i);
#pragma unroll
    for (int j = 15; j >= 1; --j) {
        float nv = le[j] ? cv[j] : (le[j - 1] ? v : cv[j - 1]);
        int   ni = le[j] ? ci[j] : (le[j - 1] ? i : ci[j - 1]);
        cv[j] = nv; ci[j] = ni;
    }
    if (!le[0]) { cv[0] = v; ci[0] = i; }
}

__device__ __forceinline__ void ins16_desc(float (&iv)[16], float v) {
    bool ge[16];
#pragma unroll
    for (int j = 0; j < 16; ++j) ge[j] = (iv[j] >= v);
#pragma unroll
    for (int j = 15; j >= 1; --j)
        iv[j] = ge[j] ? iv[j] : (ge[j - 1] ? v : iv[j - 1]);
    if (!ge[0]) iv[0] = v;
}

__device__ __forceinline__ void bitonic16_asc(float (&v)[16], int (&idx)[16]) {
#pragma unroll
    for (int d = 8; d >= 1; d >>= 1) {
#pragma unroll
        for (int i = 0; i < 16; ++i) {
            if ((i & d) == 0) {
                float &va = v[i], &vb = v[i | d];
                int &ia = idx[i], &ib = idx[i | d];
                if (pless(vb, ib, va, ia)) {
                    float tv = va; va = vb; vb = tv;
                    int ti = ia; ia = ib; ib = ti;
                }
            }
        }
    }
}

__device__ __forceinline__ void bitonic16_desc(float (&v)[16]) {
#pragma unroll
    for (int d = 8; d >= 1; d >>= 1) {
#pragma unroll
        for (int i = 0; i < 16; ++i) {
            if ((i & d) == 0) {
                if (v[i | d] > v[i]) { float t = v[i]; v[i] = v[i | d]; v[i | d] = t; }
            }
        }
    }
}

__global__ __launch_bounds__(256) void kB_topk(
    const float* __restrict__ boxes,    // [BS][Qn][4]
    const float* __restrict__ tboxes,   // [BS][Gn][4]
    const float* __restrict__ out,      // cost at [b][0][g][q]
    float* __restrict__ thrv,           // [BS*Gn]
    int*   __restrict__ thri)           // [BS*Gn]
{
    const int g = blockIdx.x, b = blockIdx.y;
    const int tid = threadIdx.x;

    const float* tb = tboxes + (size_t)(b * Gn + g) * 4;
    const float tcx = tb[0], tcy = tb[1], tw = tb[2], th = tb[3];
    const float tx0 = tcx - 0.5f * tw, ty0 = tcy - 0.5f * th;
    const float tx1 = tcx + 0.5f * tw, ty1 = tcy + 0.5f * th;
    const float tarea = (tx1 - tx0) * (ty1 - ty0);

    const float* crow = out + (size_t)(b * 2 * Gn + g) * Qn;
    const float4* brow = reinterpret_cast<const float4*>(boxes) + (size_t)b * Qn;

    float cv[16]; int ci[16]; float iv[16];
#pragma unroll
    for (int j = 0; j < 16; ++j) { cv[j] = INFINITY; ci[j] = INT_MAX; iv[j] = -INFINITY; }

    for (int q = tid; q < Qn; q += 256) {
        const float c = crow[q];
        if (pless(c, q, cv[15], ci[15])) ins16_pair(cv, ci, c, q);

        const float4 bb = brow[q];
        const float x0 = bb.x - 0.5f * bb.z, y0 = bb.y - 0.5f * bb.w;
        const float x1 = bb.x + 0.5f * bb.z, y1 = bb.y + 0.5f * bb.w;
        const float area1 = (x1 - x0) * (y1 - y0);
        const float ltx = fmaxf(x0, tx0), lty = fmaxf(y0, ty0);
        const float rbx = fminf(x1, tx1), rby = fminf(y1, ty1);
        const float iw = fmaxf(rbx - ltx, 0.0f), ih = fmaxf(rby - lty, 0.0f);
        const float inter = iw * ih;
        const float uni = (area1 + tarea) - inter;
        const float iou = inter / (uni + kEPS);
        if (iou > iv[15]) ins16_desc(iv, iou);
    }

    __shared__ float s_cv[256][16];
    __shared__ int   s_ci[256][16];
    __shared__ float s_iv[256][16];
#pragma unroll
    for (int j = 0; j < 16; ++j) { s_cv[tid][j] = cv[j]; s_ci[tid][j] = ci[j]; s_iv[tid][j] = iv[j]; }

    for (int half = 128; half >= 1; half >>= 1) {
        __syncthreads();
        if (tid < half) {
            const int p = tid + half;
            // merge: A asc ++ reverse(B) is bitonic; keep elementwise min -> 16 smallest
#pragma unroll
            for (int j = 0; j < 16; ++j) {
                const float bv = s_cv[p][15 - j]; const int bi = s_ci[p][15 - j];
                if (pless(bv, bi, cv[j], ci[j])) { cv[j] = bv; ci[j] = bi; }
                const float jv = s_iv[p][15 - j];
                if (jv > iv[j]) iv[j] = jv;
            }
            bitonic16_asc(cv, ci);
            bitonic16_desc(iv);
#pragma unroll
            for (int j = 0; j < 16; ++j) { s_cv[tid][j] = cv[j]; s_ci[tid][j] = ci[j]; s_iv[tid][j] = iv[j]; }
        }
    }

    if (tid == 0) {
        float s = 0.0f;
#pragma unroll
        for (int j = 0; j < 10; ++j) s += iv[j];   // descending order, like top_k output
        int k = (int)s;                            // astype(int32): trunc toward 0
        if (k < 1) k = 1;                          // clip(., 1)
        thrv[b * Gn + g] = cv[k - 1];
        thri[b * Gn + g] = ci[k - 1];
    }
}

// ---------------------------------------------------------------------------
// Phase C: per anchor column q: matching + (>1 matched) argmin fixup.
// ---------------------------------------------------------------------------
__global__ __launch_bounds__(256) void kC_match(
    const float* __restrict__ outc,     // cost at [b][0][g][q]
    const float* __restrict__ thrv,
    const int*   __restrict__ thri,
    float* __restrict__ out)            // matching at [b][1][g][q]
{
    const int b = blockIdx.y;
    const int q = blockIdx.x * 256 + threadIdx.x;

    __shared__ float s_tv[Gn];
    __shared__ int   s_ti[Gn];
    if (threadIdx.x < Gn) {
        s_tv[threadIdx.x] = thrv[b * Gn + threadIdx.x];
        s_ti[threadIdx.x] = thri[b * Gn + threadIdx.x];
    }
    __syncthreads();
    if (q >= Qn) return;

    const float* crow = outc + (size_t)(b * 2) * Gn * Qn + q;
    unsigned long long m0 = 0, m1 = 0;
    float minc = INFINITY;
    int ming = 0;
    for (int g = 0; g < Gn; ++g) {
        const float c = crow[(size_t)g * Qn];
        const bool mt = (c < s_tv[g]) || (c == s_tv[g] && q <= s_ti[g]);
        if (g < 64) m0 |= (unsigned long long)mt << g;
        else        m1 |= (unsigned long long)mt << (g - 64);
        if (c < minc) { minc = c; ming = g; }   // strict: first argmin
    }
    const int cnt = __popcll(m0) + __popcll(m1);
    const bool fix = (cnt > 1);

    float* mrow = out + (size_t)(b * 2 + 1) * Gn * Qn + q;
    for (int g = 0; g < Gn; ++g) {
        const bool bit = (g < 64) ? ((m0 >> g) & 1ull) : ((m1 >> (g - 64)) & 1ull);
        const bool mt = fix ? (g == ming) : bit;
        mrow[(size_t)g * Qn] = mt ? 1.0f : 0.0f;
    }
}

// ---------------------------------------------------------------------------
extern "C" void kernel_launch(void* const* d_in, const int* in_sizes, int n_in,
                              void* d_out, int out_size, void* d_ws, size_t ws_size,
                              hipStream_t stream) {
    (void)in_sizes; (void)n_in; (void)out_size; (void)ws_size;
    const float* logits = (const float*)d_in[0];
    const float* boxes  = (const float*)d_in[1];
    const int*   labels = (const int*)d_in[2];
    const float* tboxes = (const float*)d_in[3];
    float* out = (float*)d_out;

    float* thrv = (float*)d_ws;                                   // [BS*Gn]
    int*   thri = (int*)((char*)d_ws + (size_t)BS * Gn * sizeof(float));

    dim3 gA((Qn + 255) / 256, Gn / 16, BS);
    kA_cost<<<gA, 256, 0, stream>>>(logits, boxes, labels, tboxes, out);

    dim3 gB(Gn, BS);
    kB_topk<<<gB, 256, 0, stream>>>(boxes, tboxes, out, thrv, thri);

    dim3 gC((Qn + 255) / 256, BS);
    kC_match<<<gC, 256, 0, stream>>>(out, thrv, thri, out);
}